// Round 10
// baseline (238.199 us; speedup 1.0000x reference)
//
#include <hip/hip_runtime.h>

// GRU teacher-forced NLL, B=8192, S=2048, H=8, IN_DIM=4, NCLS=10.
// R26: dual-stream ILP. R25 was a diagnostic null: packing cut reported
// VALUBusy 83->77% (-38 cyc/step, as predicted) with ZERO time change ->
// no longer issue-bound. Wall 566 cyc/step vs ~200 true issue; Occupancy
// pinned ~44% (3.5 eff waves/SIMD) across R19/R24/R25 -> per-step serial
// chain (MFMA -> 11-op gate chain w/ 5 trans -> cvt -> permlane -> MFMA)
// is exposed. Fix: each wave runs TWO independent GRU streams (chunks
// 2c, 2c+1 of the same 32 batch elems): MFMA_A + MFMA_B issued back-to-back,
// then chain_A (hides B's MFMA latency), then chain_B. Grid 1024 blocks
// (64 b-groups x 16 chunk-pairs) = 4 blocks/CU, 16 waves/CU @ VGPR<=128.
// Per-stream math EXACTLY R25 (absmax 0.0). Named structs GA/GB (rule #20:
// no runtime-indexed state -> no scratch). Chunk-0 (no warm) handled by a
// block-uniform branch: B warms solo in pair-block 0.
//
// MFMA layout (v_mfma_f32_32x32x16_f16, one per stream-step):
//   rows 0-7  = r-gate   (S1 * [Whr | Wir]),  bias S1*(bir+bhr) via C
//   rows 8-15 = z-gate   (S1 * [Whz | Wiz]),  bias S1*(biz+bhz) via C
//   rows 16-23= n h-part (2S1 * [Whn | 0 ]),  bias 2S1*bhn      via C
//   rows 24-31= logits 0-7 (S1 * [Wout | 0]), bias S1*bout      via C
//   K: k0-7 = h (f16), k8-11 = x bits, k12-15 = 0. cols = 32 batch elems.

#define SEQ    2048
#define BATCH  8192
#define WARM   16
#define CLEN   64

using hh2    = decltype(__builtin_amdgcn_cvt_pkrtz(0.0f, 0.0f));
using f16x8  = __attribute__((ext_vector_type(8))) _Float16;
using f32x2  = __attribute__((ext_vector_type(2))) float;
using f32x16 = __attribute__((ext_vector_type(16))) float;
using i32x4  = __attribute__((ext_vector_type(4))) int;

#if defined(__has_builtin)
# if __has_builtin(__builtin_amdgcn_permlane32_swap)
#  define HAVE_PLS 1
# endif
#endif
#ifndef HAVE_PLS
# define HAVE_PLS 0
#endif

static __device__ __forceinline__ float dot2(hh2 a, hh2 b, float c) {
    return __builtin_amdgcn_fdot2(a, b, c, false);
}
static __device__ __forceinline__ f32x2 fma2(f32x2 a, f32x2 b, f32x2 c) {
    return __builtin_elementwise_fma(a, b, c);   // -> v_pk_fma_f32
}
static __device__ __forceinline__ f32x2 exp2n2(f32x2 a) {   // {2^-x, 2^-y}
    f32x2 r;
    r.x = __builtin_amdgcn_exp2f(-a.x);
    r.y = __builtin_amdgcn_exp2f(-a.y);
    return r;
}
static __device__ __forceinline__ f32x2 exp22(f32x2 a) {
    f32x2 r;
    r.x = __builtin_amdgcn_exp2f(a.x);
    r.y = __builtin_amdgcn_exp2f(a.y);
    return r;
}
static __device__ __forceinline__ f32x2 rcp2(f32x2 a) {
    f32x2 r;
    r.x = __builtin_amdgcn_rcpf(a.x);
    r.y = __builtin_amdgcn_rcpf(a.y);
    return r;
}

struct BTrue  { static constexpr bool value = true;  };
struct BFalse { static constexpr bool value = false; };

struct GS {                       // one GRU stream's live state
    const int4* p4;
    int    cnt;
    float4 gz4;
    int    xw0, xw1;
    f32x2  hp01, hp23;
    int    own01, own23;
    float  P;
};

__global__ __launch_bounds__(256, 4)
void gru_nll_kernel(const int* __restrict__ xb,
                    const float* __restrict__ Wir, const float* __restrict__ bir,
                    const float* __restrict__ Wiz, const float* __restrict__ biz,
                    const float* __restrict__ Win, const float* __restrict__ bin_,
                    const float* __restrict__ Whr, const float* __restrict__ bhr,
                    const float* __restrict__ Whz, const float* __restrict__ bhz,
                    const float* __restrict__ Whn, const float* __restrict__ bhn,
                    const float* __restrict__ Wout, const float* __restrict__ bout,
                    float* __restrict__ out)
{
    constexpr float S1 = 1.4426950408889634f;   // log2(e)
    __shared__ float4 tblg[10][2];   // [count][half] = 2*S1*(Win·x + bin) comps 4h..4h+3
    __shared__ float2 tblx[10];      // [count] = packed f16 x-bits {x0,x1},{x2,x3}
    __shared__ float4 tblw[10][2];   // [count][half] = {f16 w01, f16 w23, w89, 0}
    __shared__ float  red[256];

    const int tid = threadIdx.x;

    if (tid < 20) {
        int c = tid >> 1, h2 = tid & 1;
        float b0 = (float)((c >> 3) & 1);
        float b1 = (float)((c >> 2) & 1);
        float b2 = (float)((c >> 1) & 1);
        float b3 = (float)(c & 1);
        float4 v;
        float* vp = (float*)&v;
        #pragma unroll
        for (int j = 0; j < 4; ++j) {
            int ii = h2 * 4 + j;
            float gn = bin_[ii] + b0*Win[ii*4+0] + b1*Win[ii*4+1]
                                + b2*Win[ii*4+2] + b3*Win[ii*4+3];
            vp[j] = 2.0f * S1 * gn;
        }
        tblg[c][h2] = v;
        float w0 = (c == 4*h2 + 0) ? 1.0f : 0.0f;
        float w1 = (c == 4*h2 + 1) ? 1.0f : 0.0f;
        float w2 = (c == 4*h2 + 2) ? 1.0f : 0.0f;
        float w3 = (c == 4*h2 + 3) ? 1.0f : 0.0f;
        float w89 = (c == 8 + h2) ? 1.0f : 0.0f;
        hh2 w01h = __builtin_amdgcn_cvt_pkrtz(w0, w1);
        hh2 w23h = __builtin_amdgcn_cvt_pkrtz(w2, w3);
        tblw[c][h2] = make_float4(__builtin_bit_cast(float, w01h),
                                  __builtin_bit_cast(float, w23h), w89, 0.0f);
        if (h2 == 0) {
            hh2 plo = __builtin_amdgcn_cvt_pkrtz(b0, b1);
            hh2 phi = __builtin_amdgcn_cvt_pkrtz(b2, b3);
            tblx[c] = make_float2(__builtin_bit_cast(float, plo),
                                  __builtin_bit_cast(float, phi));
        }
    }
    __syncthreads();

    const int wid  = tid >> 6;
    const int lane = tid & 63;
    const int col  = lane & 31;
    const int hi   = lane >> 5;
    const bool lo  = (hi == 0);

    const int cpair  = blockIdx.x & 15;            // block-uniform chunk pair
    const int chunkA = cpair * 2;                  // may be 0 (no warm)
    const int chunkB = cpair * 2 + 1;              // never 0
    const int b      = (blockIdx.x >> 4) * 128 + wid * 32 + col;

    // ---- A fragment
    const int row = lane & 31;
    const int g   = row >> 3;
    const int rr_ = row & 7;
    f16x8 af;
    #pragma unroll
    for (int e = 0; e < 8; ++e) {
        int k = hi * 8 + e;
        float w = 0.0f;
        if (k < 8) {
            if      (g == 0) w = S1       * Whr[rr_*8 + k];
            else if (g == 1) w = S1       * Whz[rr_*8 + k];
            else if (g == 2) w = 2.0f*S1  * Whn[rr_*8 + k];
            else             w = S1       * Wout[rr_*8 + k];
        } else if (k < 12) {
            int xi = k - 8;
            if      (g == 0) w = S1 * Wir[rr_*4 + xi];
            else if (g == 1) w = S1 * Wiz[rr_*4 + xi];
        }
        af[e] = (_Float16)w;
    }

    // ---- C bias
    f32x16 cb;
    #pragma unroll
    for (int r2 = 0; r2 < 16; ++r2) {
        int rw = (r2 & 3) + 8 * (r2 >> 2) + 4 * hi;
        int gg = rw >> 3, cp = rw & 7;
        float v;
        if      (gg == 0) v = S1 * (bir[cp] + bhr[cp]);
        else if (gg == 1) v = S1 * (biz[cp] + bhz[cp]);
        else if (gg == 2) v = 2.0f * S1 * bhn[cp];
        else              v = S1 * bout[(r2 & 3) + 4 * hi];
        cb[r2] = v;
    }

    // ---- class 8/9 weights, (own, other) comp order
    const int cls89 = 8 + hi;
    hh2 wc89[4];
    #pragma unroll
    for (int q = 0; q < 4; ++q) {
        int base_ = ((q < 2) ? 4 * hi : 4 * (1 - hi)) + (q & 1) * 2;
        wc89[q] = __builtin_amdgcn_cvt_pkrtz(S1 * Wout[cls89*8 + base_],
                                             S1 * Wout[cls89*8 + base_ + 1]);
    }
    const float b89 = S1 * bout[cls89];

    // ---- permlane32_swap: partner = rr[1] on lanes<32, rr[0] on lanes>=32
#if HAVE_PLS
    bool useR1;
    {
        unsigned probe = lo ? 0u : 1u;
        unsigned want  = 1u - probe;
        auto rr = __builtin_amdgcn_permlane32_swap(probe, probe, false, false);
        useR1 = (rr[1] == want);
    }
    auto swp = [&](int v) {
        auto rr = __builtin_amdgcn_permlane32_swap((unsigned)v, (unsigned)v,
                                                   false, false);
        return make_int2((int)rr[0], (int)rr[1]);
    };
    auto psel = [&](int2 r) -> int { return useR1 ? r.y : r.x; };
#else
    auto swp = [&](int v) { int p = __shfl_xor(v, 32, 64); return make_int2(v, p); };
    auto psel = [&](int2 r) -> int { return r.y; };
#endif

    const float4* tg = &tblg[0][hi];
    const float4* tw = &tblw[0][hi];
    const f32x2 one2 = {1.0f, 1.0f};

    float accp = 0.f, acct = 0.f;

    GS GA, GB;
    {
        const int* bb = xb + (size_t)b * SEQ;
        int tsA = chunkA * CLEN - (chunkA ? WARM : 0);
        int tsB = chunkB * CLEN - WARM;
        GA.cnt = chunkA ? bb[tsA - 1] : 0;
        GB.cnt = bb[tsB - 1];
        GA.p4  = (const int4*)(bb + tsA);
        GB.p4  = (const int4*)(bb + tsB);
        GA.gz4 = tg[GA.cnt * 2];
        GB.gz4 = tg[GB.cnt * 2];
        float2 xA = tblx[GA.cnt], xB2 = tblx[GB.cnt];
        GA.xw0 = __builtin_bit_cast(int, xA.x);
        GA.xw1 = __builtin_bit_cast(int, xA.y);
        GB.xw0 = __builtin_bit_cast(int, xB2.x);
        GB.xw1 = __builtin_bit_cast(int, xB2.y);
        GA.hp01 = {0.f,0.f}; GA.hp23 = {0.f,0.f}; GA.own01 = 0; GA.own23 = 0; GA.P = 1.f;
        GB.hp01 = {0.f,0.f}; GB.hp23 = {0.f,0.f}; GB.own01 = 0; GB.own23 = 0; GB.P = 1.f;
    }

    // ---- one stream's chain AFTER its MFMA result is available
    auto backhalf = [&](GS& S, f32x16 d, int2 s01, int2 s23, float4 w4,
                        int cnext, auto lossc) {
        constexpr bool LOSS = decltype(lossc)::value;
        float4 gzn = tg[cnext * 2];
        float2 xbn = tblx[cnext];

        float l89;
        if constexpr (LOSS) {
            int o01 = psel(s01), o23 = psel(s23);
            l89 = b89;
            l89 = dot2(__builtin_bit_cast(hh2, S.own01), wc89[0], l89);
            l89 = dot2(__builtin_bit_cast(hh2, S.own23), wc89[1], l89);
            l89 = dot2(__builtin_bit_cast(hh2, o01),     wc89[2], l89);
            l89 = dot2(__builtin_bit_cast(hh2, o23),     wc89[3], l89);
        }

        f32x2 ar01 = {d[0], d[1]},  ar23 = {d[2], d[3]};
        f32x2 az01 = {d[4], d[5]},  az23 = {d[6], d[7]};
        f32x2 hn01 = {d[8], d[9]},  hn23 = {d[10], d[11]};
        f32x2 gz01 = {S.gz4.x, S.gz4.y}, gz23 = {S.gz4.z, S.gz4.w};

        f32x2 er01 = exp2n2(ar01), er23 = exp2n2(ar23);
        f32x2 ez01 = exp2n2(az01), ez23 = exp2n2(az23);
        f32x2 ir01 = rcp2(er01 + one2), ir23 = rcp2(er23 + one2);
        f32x2 u01  = fma2(hn01, ir01, gz01), u23 = fma2(hn23, ir23, gz23);
        f32x2 E01  = exp22(u01),   E23 = exp22(u23);
        f32x2 a01  = E01 + one2,   a23 = E23 + one2;
        f32x2 c01  = E01 - one2,   c23 = E23 - one2;
        f32x2 m01  = ez01 * c01,   m23 = ez23 * c23;
        f32x2 n01  = fma2(S.hp01, a01, m01), n23 = fma2(S.hp23, a23, m23);
        f32x2 t01  = ez01 + one2,  t23 = ez23 + one2;
        f32x2 id01 = rcp2(a01 * t01), id23 = rcp2(a23 * t23);
        f32x2 h01  = n01 * id01,   h23 = n23 * id23;

        S.hp01 = h01; S.hp23 = h23;
        S.own01 = __builtin_bit_cast(int, __builtin_amdgcn_cvt_pkrtz(h01.x, h01.y));
        S.own23 = __builtin_bit_cast(int, __builtin_amdgcn_cvt_pkrtz(h23.x, h23.y));

        if constexpr (LOSS) {
            float l0 = d[12], l1 = d[13], l2 = d[14], l3 = d[15];
            float e0 = __builtin_amdgcn_exp2f(l0);
            float e1 = __builtin_amdgcn_exp2f(l1);
            float e2 = __builtin_amdgcn_exp2f(l2);
            float e3 = __builtin_amdgcn_exp2f(l3);
            float e8 = __builtin_amdgcn_exp2f(l89);
            float so = ((e0 + e1) + (e2 + e3)) + e8;
            int2 ss = swp(__builtin_bit_cast(int, so));
            float st = __builtin_bit_cast(float, ss.x)
                     + __builtin_bit_cast(float, ss.y);
            S.P *= st;
            hh2 pl01 = __builtin_amdgcn_cvt_pkrtz(l0, l1);
            hh2 pl23 = __builtin_amdgcn_cvt_pkrtz(l2, l3);
            float sel = w4.z * l89;
            sel = dot2(pl23, __builtin_bit_cast(hh2, w4.y), sel);
            sel = dot2(pl01, __builtin_bit_cast(hh2, w4.x), sel);
            acct += sel;
        }
        S.cnt = cnext;
        S.gz4 = gzn;
        S.xw0 = __builtin_bit_cast(int, xbn.x);
        S.xw1 = __builtin_bit_cast(int, xbn.y);
    };

    // ---- paired step: both MFMAs in flight before either chain runs
    auto pairstep = [&](int cA, int cB, auto lossc) {
        constexpr bool LOSS = decltype(lossc)::value;
        float4 w4A, w4B;
        if constexpr (LOSS) { w4A = tw[GA.cnt * 2]; w4B = tw[GB.cnt * 2]; }
        int2 sA01 = swp(GA.own01), sA23 = swp(GA.own23);
        i32x4 bwA = {lo ? GA.own01 : GA.xw0, lo ? GA.own23 : GA.xw1, sA01.y, sA23.y};
        f32x16 dA = __builtin_amdgcn_mfma_f32_32x32x16_f16(
            af, __builtin_bit_cast(f16x8, bwA), cb, 0, 0, 0);
        int2 sB01 = swp(GB.own01), sB23 = swp(GB.own23);
        i32x4 bwB = {lo ? GB.own01 : GB.xw0, lo ? GB.own23 : GB.xw1, sB01.y, sB23.y};
        f32x16 dB = __builtin_amdgcn_mfma_f32_32x32x16_f16(
            af, __builtin_bit_cast(f16x8, bwB), cb, 0, 0, 0);
        backhalf(GA, dA, sA01, sA23, w4A, cA, lossc);
        backhalf(GB, dB, sB01, sB23, w4B, cB, lossc);
    };

    auto solostep = [&](GS& S, int cnext, auto lossc) {
        constexpr bool LOSS = decltype(lossc)::value;
        float4 w4;
        if constexpr (LOSS) w4 = tw[S.cnt * 2];
        int2 s01 = swp(S.own01), s23 = swp(S.own23);
        i32x4 bw = {lo ? S.own01 : S.xw0, lo ? S.own23 : S.xw1, s01.y, s23.y};
        f32x16 d = __builtin_amdgcn_mfma_f32_32x32x16_f16(
            af, __builtin_bit_cast(f16x8, bw), cb, 0, 0, 0);
        backhalf(S, d, s01, s23, w4, cnext, lossc);
    };

    const int wbA = chunkA ? (WARM / 4) : 0;       // block-uniform
    const int wbB = WARM / 4;

    int4 ccA = GA.p4[0];
    int4 ccB = GB.p4[0];
    pairstep(ccA.x, ccB.x, BFalse{});              // iter0 both streams

    if (chunkA) {                                  // both warm (interleaved)
        for (int jb = 0; jb < WARM/4; ++jb) {
            int4 nA = GA.p4[jb + 1];
            int4 nB = GB.p4[jb + 1];
            pairstep(ccA.y, ccB.y, BFalse{});
            pairstep(ccA.z, ccB.z, BFalse{});
            pairstep(ccA.w, ccB.w, BFalse{});
            pairstep(nA.x,  nB.x,  BFalse{});
            ccA = nA; ccB = nB;
        }
    } else {                                       // A = chunk 0: B warms solo
        for (int jb = 0; jb < WARM/4; ++jb) {
            int4 nB = GB.p4[jb + 1];
            solostep(GB, ccB.y, BFalse{});
            solostep(GB, ccB.z, BFalse{});
            solostep(GB, ccB.w, BFalse{});
            solostep(GB, nB.x,  BFalse{});
            ccB = nB;
        }
    }

    for (int k = 0; k < CLEN/4; ++k) {             // 16 paired loss iters
        bool more = (k + 1 < CLEN/4);
        int4 nA = GA.p4[more ? (wbA + k + 1) : 0];
        int4 nB = GB.p4[more ? (wbB + k + 1) : 0];
        pairstep(ccA.y, ccB.y, BTrue{});
        pairstep(ccA.z, ccB.z, BTrue{});
        pairstep(ccA.w, ccB.w, BTrue{});
        pairstep(nA.x,  nB.x,  BTrue{});
        ccA = nA; ccB = nB;
        if (k & 1) {
            accp += __builtin_amdgcn_logf(GA.P) + __builtin_amdgcn_logf(GB.P);
            GA.P = 1.0f; GB.P = 1.0f;
        }
    }

    // accp duplicated across the lane pair -> x0.5; acct is not.
    red[tid] = __builtin_fmaf(accp, 0.5f, -acct);
    __syncthreads();
    #pragma unroll
    for (int sft = 128; sft > 0; sft >>= 1) {
        if (tid < sft) red[tid] += red[tid + sft];
        __syncthreads();
    }
    if (tid == 0) {
        constexpr float SCALE =
            (float)(0.69314718055994530942 / (8192.0 * 2048.0));
        atomicAdd(out, red[0] * SCALE);
    }
}

extern "C" void kernel_launch(void* const* d_in, const int* in_sizes, int n_in,
                              void* d_out, int out_size, void* d_ws, size_t ws_size,
                              hipStream_t stream) {
    (void)hipMemsetAsync(d_out, 0, sizeof(float), stream);
    // 64 batch-groups (128 elems: 4 waves x 32) x 16 chunk-PAIRS = 1024 blocks
    // = 4 blocks/CU, 16 waves/CU; 2 GRU streams per wave (intra-wave ILP).
    gru_nll_kernel<<<1024, 256, 0, stream>>>(
        (const int*)d_in[0],
        (const float*)d_in[1],  (const float*)d_in[2],
        (const float*)d_in[3],  (const float*)d_in[4],
        (const float*)d_in[5],  (const float*)d_in[6],
        (const float*)d_in[7],  (const float*)d_in[8],
        (const float*)d_in[9],  (const float*)d_in[10],
        (const float*)d_in[11], (const float*)d_in[12],
        (const float*)d_in[13], (const float*)d_in[14],
        (float*)d_out);
}